// Round 3
// baseline (410.031 us; speedup 1.0000x reference)
//
#include <hip/hip_runtime.h>
#include <math.h>

#define NTOK 32768          // B*S = 4*8192
#define HDIM 2048
#define K_SEL 22937         // int(0.7 * 32768)
#define EPS_F 1e-10f
#define NBLK 8192           // score blocks: 4 tokens per block, 1 per wave

// ---------------------------------------------------------------------------
// Kernel 1: per-token score (dot of 2048 floats), gumbel noise, sortable key.
// EXACTLY R1's memory shape (1 token/wave, 8 independent float4 loads/lane,
// wave retires immediately) — R1 hit 223us only because of 16384 contended
// global atomics; those are replaced by per-block partial stores.
// Summation order bit-identical to R1/R2 (both passed).
// ---------------------------------------------------------------------------
__global__ __launch_bounds__(256) void score_kernel(
    const float* __restrict__ hidden,
    const float* __restrict__ u,
    const float* __restrict__ w,
    const float* __restrict__ b,
    unsigned int* __restrict__ keys,
    float* __restrict__ pp,   // [NBLK] per-block sum of sigmoid(score)
    float* __restrict__ zz)   // [NBLK] per-block sum of score^2
{
    const int wave = threadIdx.x >> 6;
    const int lane = threadIdx.x & 63;
    const int token = blockIdx.x * 4 + wave;

    const float4* __restrict__ hrow = (const float4*)(hidden + (size_t)token * HDIM);
    const float4* __restrict__ w4   = (const float4*)w;

    float sum = 0.0f;
    #pragma unroll
    for (int j = 0; j < 8; ++j) {
        const int idx = j * 64 + lane;          // coalesced 16B/lane
        const float4 hv = hrow[idx];
        const float4 wv = w4[idx];
        sum += hv.x * wv.x + hv.y * wv.y + hv.z * wv.z + hv.w * wv.w;
    }
    #pragma unroll
    for (int off = 32; off > 0; off >>= 1)
        sum += __shfl_down(sum, off, 64);

    __shared__ float red_p[4], red_z[4];
    if (lane == 0) {
        const float score = sum + b[0];
        const float uu = u[token];
        const float g = -logf(-logf(uu + EPS_F) + EPS_F);
        const float noisy = (score + g) * 2.0f;     // /TEMP, TEMP=0.5
        const unsigned int bits = __float_as_uint(noisy);
        keys[token] = (bits & 0x80000000u) ? ~bits : (bits | 0x80000000u);
        red_p[wave] = 1.0f / (1.0f + expf(-score));
        red_z[wave] = score * score;
    }
    __syncthreads();
    if (threadIdx.x == 0) {
        pp[blockIdx.x] = red_p[0] + red_p[1] + red_p[2] + red_p[3];
        zz[blockIdx.x] = red_z[0] + red_z[1] + red_z[2] + red_z[3];
    }
}

// ---------------------------------------------------------------------------
// Kernel 2: single workgroup, 1024 threads, 32 keys/thread in registers.
// 32-step bitwise binary search for the k-th largest key tau, then
// lowest-index-first tie-break (matches jax.lax.top_k), mask write, and the
// aux-loss reduction over the 8192 per-block partials.
// All global reads of `keys` happen before any `out` write (aliasing-safe).
// ---------------------------------------------------------------------------
__global__ __launch_bounds__(1024) void select_kernel(
    const unsigned int* __restrict__ keys,
    const float* __restrict__ pp,
    const float* __restrict__ zz,
    float* __restrict__ out)
{
    __shared__ unsigned int wcnt[16];
    __shared__ float wredp[16], wredz[16];
    __shared__ unsigned int wtot[16], woff[16];

    const int t = threadIdx.x;
    const int lane = t & 63;
    const int wid = t >> 6;
    const int base = t * 32;

    unsigned int myk[32];
    #pragma unroll
    for (int j = 0; j < 32; ++j) myk[j] = keys[base + j];

    // ---- tau = k-th largest key: find max x with count(key >= x) >= K ----
    unsigned int tau = 0u;
    for (int bit = 31; bit >= 0; --bit) {
        const unsigned int cand = tau | (1u << bit);
        unsigned int c = 0u;
        #pragma unroll
        for (int j = 0; j < 32; ++j) c += (myk[j] >= cand) ? 1u : 0u;
        #pragma unroll
        for (int off = 32; off > 0; off >>= 1) c += __shfl_down(c, off, 64);
        if (lane == 0) wcnt[wid] = c;
        __syncthreads();
        unsigned int tot = 0u;
        #pragma unroll
        for (int i = 0; i < 16; ++i) tot += wcnt[i];
        if (tot >= (unsigned int)K_SEL) tau = cand;
        __syncthreads();   // protect wcnt reuse next iteration
    }

    // ---- how many ==tau to take (lowest index first) ----
    unsigned int cgt = 0u;
    #pragma unroll
    for (int j = 0; j < 32; ++j) cgt += (myk[j] > tau) ? 1u : 0u;
    unsigned int cg = cgt;
    #pragma unroll
    for (int off = 32; off > 0; off >>= 1) cg += __shfl_down(cg, off, 64);
    if (lane == 0) wcnt[wid] = cg;
    __syncthreads();
    unsigned int tot_gt = 0u;
    #pragma unroll
    for (int i = 0; i < 16; ++i) tot_gt += wcnt[i];
    const unsigned int needed = (unsigned int)K_SEL - tot_gt;

    // ---- exclusive scan (index order) of per-chunk equal counts ----
    unsigned int ceq = 0u;
    #pragma unroll
    for (int j = 0; j < 32; ++j) ceq += (myk[j] == tau) ? 1u : 0u;
    unsigned int v = ceq;
    #pragma unroll
    for (int off = 1; off < 64; off <<= 1) {
        const unsigned int n = __shfl_up(v, off, 64);
        if (lane >= off) v += n;
    }
    __syncthreads();
    if (lane == 63) wtot[wid] = v;
    __syncthreads();
    if (t == 0) {
        unsigned int run = 0u;
        for (int i = 0; i < 16; ++i) { woff[i] = run; run += wtot[i]; }
    }
    __syncthreads();
    unsigned int rank = woff[wid] + (v - ceq);

    // ---- write 0/1 mask ----
    #pragma unroll
    for (int j = 0; j < 32; ++j) {
        const unsigned int kk = myk[j];
        float val;
        if (kk > tau) {
            val = 1.0f;
        } else if (kk == tau) {
            val = (rank < needed) ? 1.0f : 0.0f;
            rank++;
        } else {
            val = 0.0f;
        }
        out[base + j] = val;
    }

    // ---- aux loss: reduce the 8192 per-block partials (stride-1024 = coalesced)
    float lp = 0.0f, lz = 0.0f;
    #pragma unroll
    for (int i = 0; i < 8; ++i) {
        lp += pp[t + i * 1024];
        lz += zz[t + i * 1024];
    }
    #pragma unroll
    for (int off = 32; off > 0; off >>= 1) {
        lp += __shfl_down(lp, off, 64);
        lz += __shfl_down(lz, off, 64);
    }
    if (lane == 0) { wredp[wid] = lp; wredz[wid] = lz; }
    __syncthreads();
    if (t == 0) {
        float sp = 0.0f, sz = 0.0f;
        for (int i = 0; i < 16; ++i) { sp += wredp[i]; sz += wredz[i]; }
        const float na = (float)NTOK;
        const float f = (float)K_SEL / na;
        const float p = sp / na;
        const float z = sz / na;
        const float d1 = f - 0.7f;
        const float d2 = p - 0.7f;
        out[NTOK] = 0.005f * (d1 * d1 + d2 * d2) + 5e-6f * z;
    }
}

extern "C" void kernel_launch(void* const* d_in, const int* in_sizes, int n_in,
                              void* d_out, int out_size, void* d_ws, size_t ws_size,
                              hipStream_t stream) {
    const float* hidden = (const float*)d_in[0];
    // d_in[1] = active_mask: all-true by construction, unused
    const float* u = (const float*)d_in[2];
    const float* w = (const float*)d_in[3];
    const float* b = (const float*)d_in[4];
    float* out = (float*)d_out;

    const size_t KEYS_BYTES = (size_t)NTOK * sizeof(unsigned int);   // 128 KiB
    const size_t PART_BYTES = (size_t)NBLK * sizeof(float);          // 32 KiB

    unsigned int* keys;
    float *pp, *zz;
    if (ws_size >= KEYS_BYTES + 2 * PART_BYTES) {
        keys = (unsigned int*)d_ws;
        pp = (float*)((char*)d_ws + KEYS_BYTES);
        zz = pp + NBLK;
    } else {
        // fallback: stash keys in d_out (select reads all keys before writing
        // any output, so aliasing is safe); partials at ws start.
        keys = (unsigned int*)d_out;
        pp = (float*)d_ws;
        zz = pp + NBLK;
    }

    score_kernel<<<NBLK, 256, 0, stream>>>(hidden, u, w, b, keys, pp, zz);
    select_kernel<<<1, 1024, 0, stream>>>(keys, pp, zz, out);
}

// Round 4
// 404.851 us; speedup vs baseline: 1.0128x; 1.0128x over previous
//
#include <hip/hip_runtime.h>
#include <math.h>

#define NTOK 32768          // B*S = 4*8192
#define HDIM 2048
#define K_SEL 22937         // int(0.7 * 32768)
#define EPS_F 1e-10f
#define SBLK 1024           // score blocks: 32 tokens/block = 4 waves x 8 rows

// ---------------------------------------------------------------------------
// Kernel 1: per-token score (dot of 2048 floats), gumbel noise, sortable key.
// 8 rows per wave with explicit register double-buffering: row r+1's loads
// are issued BEFORE row r is consumed, so the load pipe never drains (R2/R3
// both stalled the pipe on the per-row reduce tail). All 8 shuffle-reduction
// chains run interleaved at the end; per-row arithmetic order is bit-identical
// to R1/R2/R3 (same j*64+lane layout, same shfl_down chain).
// ---------------------------------------------------------------------------
__global__ __launch_bounds__(256) void score_kernel(
    const float* __restrict__ hidden,
    const float* __restrict__ u,
    const float* __restrict__ w,
    const float* __restrict__ b,
    unsigned int* __restrict__ keys,
    float* __restrict__ pp,   // [SBLK] per-block sum of sigmoid(score)
    float* __restrict__ zz)   // [SBLK] per-block sum of score^2
{
    const int wave = threadIdx.x >> 6;
    const int lane = threadIdx.x & 63;
    const int row0 = blockIdx.x * 32 + wave * 8;

    const float4* __restrict__ w4 = (const float4*)w;
    float4 wr[8];
    #pragma unroll
    for (int j = 0; j < 8; ++j) wr[j] = w4[j * 64 + lane];

    const float4* __restrict__ rowp = (const float4*)(hidden + (size_t)row0 * HDIM);

    float sums[8];
    float4 buf[2][8];
    #pragma unroll
    for (int j = 0; j < 8; ++j) buf[0][j] = rowp[j * 64 + lane];

    #pragma unroll
    for (int r = 0; r < 8; ++r) {
        const int cur = r & 1, nxt = cur ^ 1;
        if (r < 7) {
            #pragma unroll
            for (int j = 0; j < 8; ++j)
                buf[nxt][j] = rowp[(r + 1) * 512 + j * 64 + lane];
        }
        float s = 0.0f;
        #pragma unroll
        for (int j = 0; j < 8; ++j) {
            const float4 hv = buf[cur][j];
            s += hv.x * wr[j].x + hv.y * wr[j].y + hv.z * wr[j].z + hv.w * wr[j].w;
        }
        sums[r] = s;
    }

    // 8 independent reduction chains, interleaved (per-row math identical)
    #pragma unroll
    for (int off = 32; off > 0; off >>= 1) {
        #pragma unroll
        for (int r = 0; r < 8; ++r)
            sums[r] += __shfl_down(sums[r], off, 64);
    }

    __shared__ float red_p[4], red_z[4];
    if (lane == 0) {
        const float bias = b[0];
        float p_acc = 0.0f, z_acc = 0.0f;
        #pragma unroll
        for (int r = 0; r < 8; ++r) {
            const float score = sums[r] + bias;
            const float uu = u[row0 + r];
            const float g = -logf(-logf(uu + EPS_F) + EPS_F);
            const float noisy = (score + g) * 2.0f;     // /TEMP, TEMP=0.5
            const unsigned int bits = __float_as_uint(noisy);
            keys[row0 + r] = (bits & 0x80000000u) ? ~bits : (bits | 0x80000000u);
            p_acc += 1.0f / (1.0f + expf(-score));
            z_acc += score * score;
        }
        red_p[wave] = p_acc;
        red_z[wave] = z_acc;
    }
    __syncthreads();
    if (threadIdx.x == 0) {
        pp[blockIdx.x] = red_p[0] + red_p[1] + red_p[2] + red_p[3];
        zz[blockIdx.x] = red_z[0] + red_z[1] + red_z[2] + red_z[3];
    }
}

// ---------------------------------------------------------------------------
// Kernel 2: single workgroup, 1024 threads, 32 contiguous keys/thread.
// v4: all global key reads and mask writes are coalesced uint4/float4 via an
// LDS staging buffer (padded +1 word per 32 to avoid bank conflicts) — the
// chunk-per-thread global pattern previously hit 64 cache lines per instr.
// Binary search + lowest-index tie-break logic unchanged (passed R2/R3).
// ---------------------------------------------------------------------------
__global__ __launch_bounds__(1024) void select_kernel(
    const unsigned int* __restrict__ keys,
    const float* __restrict__ pp,
    const float* __restrict__ zz,
    float* __restrict__ out)
{
    __shared__ unsigned int sbuf[8448];   // 8192 + pad(1 per 32) = 33 KB
    __shared__ unsigned int wcnt[16];
    __shared__ float wredp[16], wredz[16];
    __shared__ unsigned int wtot[16], woff[16];

    const int t = threadIdx.x;
    const int lane = t & 63;
    const int wid = t >> 6;

    // ---- coalesced key load via LDS, 4 passes of 8192 keys ----
    unsigned int myk[32];
    for (int p = 0; p < 4; ++p) {
        #pragma unroll
        for (int q = 0; q < 2; ++q) {
            const int v4idx = t + 1024 * q;          // uint4 index in segment
            const int e = 4 * v4idx;                 // element index in segment
            const uint4 kv = ((const uint4*)(keys + 8192 * p))[v4idx];
            *((uint4*)&sbuf[e + (e >> 5)]) = kv;
        }
        __syncthreads();
        const int c = t - 256 * p;                   // my chunk within this pass
        if (c >= 0 && c < 256) {
            #pragma unroll
            for (int j = 0; j < 8; ++j) {
                const uint4 kv = *((const uint4*)&sbuf[33 * c + 4 * j]);
                myk[4 * j + 0] = kv.x;
                myk[4 * j + 1] = kv.y;
                myk[4 * j + 2] = kv.z;
                myk[4 * j + 3] = kv.w;
            }
        }
        __syncthreads();
    }

    // ---- tau = k-th largest key: find max x with count(key >= x) >= K ----
    unsigned int tau = 0u;
    for (int bit = 31; bit >= 0; --bit) {
        const unsigned int cand = tau | (1u << bit);
        unsigned int c = 0u;
        #pragma unroll
        for (int j = 0; j < 32; ++j) c += (myk[j] >= cand) ? 1u : 0u;
        #pragma unroll
        for (int off = 32; off > 0; off >>= 1) c += __shfl_down(c, off, 64);
        if (lane == 0) wcnt[wid] = c;
        __syncthreads();
        unsigned int tot = 0u;
        #pragma unroll
        for (int i = 0; i < 16; ++i) tot += wcnt[i];
        if (tot >= (unsigned int)K_SEL) tau = cand;
        __syncthreads();
    }

    // ---- how many ==tau to take (lowest index first) ----
    unsigned int cgt = 0u;
    #pragma unroll
    for (int j = 0; j < 32; ++j) cgt += (myk[j] > tau) ? 1u : 0u;
    unsigned int cg = cgt;
    #pragma unroll
    for (int off = 32; off > 0; off >>= 1) cg += __shfl_down(cg, off, 64);
    if (lane == 0) wcnt[wid] = cg;
    __syncthreads();
    unsigned int tot_gt = 0u;
    #pragma unroll
    for (int i = 0; i < 16; ++i) tot_gt += wcnt[i];
    const unsigned int needed = (unsigned int)K_SEL - tot_gt;

    // ---- exclusive scan (index order) of per-chunk equal counts ----
    unsigned int ceq = 0u;
    #pragma unroll
    for (int j = 0; j < 32; ++j) ceq += (myk[j] == tau) ? 1u : 0u;
    unsigned int v = ceq;
    #pragma unroll
    for (int off = 1; off < 64; off <<= 1) {
        const unsigned int n = __shfl_up(v, off, 64);
        if (lane >= off) v += n;
    }
    __syncthreads();
    if (lane == 63) wtot[wid] = v;
    __syncthreads();
    if (t == 0) {
        unsigned int run = 0u;
        for (int i = 0; i < 16; ++i) { woff[i] = run; run += wtot[i]; }
    }
    __syncthreads();
    unsigned int rank = woff[wid] + (v - ceq);

    // ---- mask write: vals -> LDS (padded), then coalesced float4 stores ----
    for (int p = 0; p < 4; ++p) {
        const int c = t - 256 * p;
        if (c >= 0 && c < 256) {
            #pragma unroll
            for (int j = 0; j < 32; ++j) {
                const unsigned int kk = myk[j];
                float val;
                if (kk > tau) {
                    val = 1.0f;
                } else if (kk == tau) {
                    val = (rank < needed) ? 1.0f : 0.0f;
                    rank++;
                } else {
                    val = 0.0f;
                }
                const int e = 32 * c + j;
                ((float*)sbuf)[e + (e >> 5)] = val;
            }
        }
        __syncthreads();
        #pragma unroll
        for (int q = 0; q < 2; ++q) {
            const int v4idx = t + 1024 * q;
            const int e = 4 * v4idx;
            const float4 fv = *((const float4*)&((float*)sbuf)[e + (e >> 5)]);
            ((float4*)(out + 8192 * p))[v4idx] = fv;
        }
        __syncthreads();
    }

    // ---- aux loss: reduce the 1024 per-block partials ----
    float lp = pp[t], lz = zz[t];
    #pragma unroll
    for (int off = 32; off > 0; off >>= 1) {
        lp += __shfl_down(lp, off, 64);
        lz += __shfl_down(lz, off, 64);
    }
    if (lane == 0) { wredp[wid] = lp; wredz[wid] = lz; }
    __syncthreads();
    if (t == 0) {
        float sp = 0.0f, sz = 0.0f;
        for (int i = 0; i < 16; ++i) { sp += wredp[i]; sz += wredz[i]; }
        const float na = (float)NTOK;
        const float f = (float)K_SEL / na;
        const float p = sp / na;
        const float z = sz / na;
        const float d1 = f - 0.7f;
        const float d2 = p - 0.7f;
        out[NTOK] = 0.005f * (d1 * d1 + d2 * d2) + 5e-6f * z;
    }
}

extern "C" void kernel_launch(void* const* d_in, const int* in_sizes, int n_in,
                              void* d_out, int out_size, void* d_ws, size_t ws_size,
                              hipStream_t stream) {
    const float* hidden = (const float*)d_in[0];
    // d_in[1] = active_mask: all-true by construction, unused
    const float* u = (const float*)d_in[2];
    const float* w = (const float*)d_in[3];
    const float* b = (const float*)d_in[4];
    float* out = (float*)d_out;

    const size_t KEYS_BYTES = (size_t)NTOK * sizeof(unsigned int);   // 128 KiB
    const size_t PART_BYTES = (size_t)SBLK * sizeof(float);          // 4 KiB

    unsigned int* keys;
    float *pp, *zz;
    if (ws_size >= KEYS_BYTES + 2 * PART_BYTES) {
        keys = (unsigned int*)d_ws;
        pp = (float*)((char*)d_ws + KEYS_BYTES);
        zz = pp + SBLK;
    } else {
        // fallback: stash keys in d_out (select reads all keys before writing
        // any output region it hasn't already consumed); partials at ws start.
        keys = (unsigned int*)d_out;
        pp = (float*)d_ws;
        zz = pp + SBLK;
    }

    score_kernel<<<SBLK, 256, 0, stream>>>(hidden, u, w, b, keys, pp, zz);
    select_kernel<<<1, 1024, 0, stream>>>(keys, pp, zz, out);
}